// Round 5
// baseline (69.368 us; speedup 1.0000x reference)
//
#include <hip/hip_runtime.h>
#include <cstdint>

#define TPB 256
#define LOG2E 1.4426950408889634f
#define LN2   0.69314718055994531f
#define VALID_LIM (1024u << 16)   // packed < this  <=>  element is valid

__device__ __forceinline__ unsigned pack_e(float s, int key)
{
    // e = 2^(s*log2e) (no shift needed: |s|<~6 keeps e in [2^-9, 2^9])
    const float e = __builtin_amdgcn_exp2f(s * LOG2E);
    const unsigned b = __builtin_bit_cast(unsigned, e);
    const unsigned b16 = (b + 0x7FFFu + ((b >> 16) & 1u)) >> 16;   // RNE -> bf16
    return ((unsigned)key << 16) | b16;
}

__global__ __launch_bounds__(TPB, 4)
void pl_fused(const float* __restrict__ scores,
              const int* __restrict__ ranks,
              const int* __restrict__ mask,
              float* __restrict__ partials,
              unsigned* __restrict__ counter,
              float* __restrict__ out,
              int B, int nb)
{
    const int tid = threadIdx.x;
    const int row = blockIdx.x * TPB + tid;

    float per_row = 0.0f, cnt = 0.0f;

    if (row < B) {
        const float4* sp = reinterpret_cast<const float4*>(scores) + (size_t)row * 8;
        const int4*   rp = reinterpret_cast<const int4*>(ranks)  + (size_t)row * 8;
        const int4*   mp = reinterpret_cast<const int4*>(mask)   + (size_t)row * 8;

        // ---- load + pack U[j] = (key11 << 16) | bf16(e_j)
        // key = mask*1024 + rank*32 + j : unique, stable-sort order, valid<1024
        unsigned U[32];
        #pragma unroll
        for (int c = 0; c < 8; ++c) {
            const float4 sv = sp[c];
            const int4   rv = rp[c];
            const int4   qv = mp[c];
            const int j = c * 4;
            U[j+0] = pack_e(sv.x, (qv.x << 10) + (rv.x << 5) + (j+0));
            U[j+1] = pack_e(sv.y, (qv.y << 10) + (rv.y << 5) + (j+1));
            U[j+2] = pack_e(sv.z, (qv.z << 10) + (rv.z << 5) + (j+2));
            U[j+3] = pack_e(sv.w, (qv.w << 10) + (rv.w << 5) + (j+3));
        }

        // ---- payload-carrying bitonic sort (ascending); fully unrolled,
        // 2 VALU (v_min_u32/v_max_u32) per comparator, 240 comparators
        #pragma unroll
        for (int kk = 2; kk <= 32; kk <<= 1) {
            #pragma unroll
            for (int jj = kk >> 1; jj > 0; jj >>= 1) {
                #pragma unroll
                for (int i = 0; i < 32; ++i) {
                    const int l = i ^ jj;
                    if (l > i) {
                        const unsigned a = U[i], b = U[l];
                        const unsigned mn = a < b ? a : b;
                        const unsigned mh = a < b ? b : a;
                        if ((i & kk) == 0) { U[i] = mn; U[l] = mh; }
                        else               { U[i] = mh; U[l] = mn; }
                    }
                }
            }
        }

        // ---- suffix sums + grouped product logs; valid <=> p < n after sort
        int   n = 0;
        float t = 0.0f, lsum = 0.0f;
        #pragma unroll
        for (int g = 7; g >= 0; --g) {
            float pT = 1.0f, pE = 1.0f;
            #pragma unroll
            for (int q = 3; q >= 0; --q) {
                const int p = 4*g + q;
                const bool v = (U[p] < VALID_LIM);
                const float e = __builtin_bit_cast(float, U[p] << 16);  // bf16->f32
                n  += v ? 1 : 0;
                t  += v ? e : 0.0f;
                pT *= v ? t : 1.0f;
                pE *= v ? e : 1.0f;
            }
            lsum += __builtin_amdgcn_logf(pT) - __builtin_amdgcn_logf(pE);  // hw log2
        }

        if (n >= 2) {
            per_row = (LN2 * lsum) / (float)n;
            cnt = 1.0f;
        }
    }

    // ---- block reduction
    #pragma unroll
    for (int d = 32; d >= 1; d >>= 1) {
        per_row += __shfl_xor(per_row, d, 64);
        cnt     += __shfl_xor(cnt,     d, 64);
    }
    __shared__ float rbuf[8];
    __shared__ bool  amLast;
    if ((tid & 63) == 0) {
        rbuf[(tid >> 6)]     = per_row;
        rbuf[4 + (tid >> 6)] = cnt;
    }
    __syncthreads();
    if (tid == 0) {
        partials[2*blockIdx.x]     = (rbuf[0] + rbuf[1]) + (rbuf[2] + rbuf[3]);
        partials[2*blockIdx.x + 1] = (rbuf[4] + rbuf[5]) + (rbuf[6] + rbuf[7]);
        __threadfence();                            // publish partials (device scope)
        const unsigned prev = atomicAdd(counter, 1u);
        amLast = (prev == (unsigned)(nb - 1));
    }
    __syncthreads();

    // ---- last block folds all partials (deterministic order)
    if (amLast) {
        __threadfence();                            // acquire partials
        float s = 0.0f, c = 0.0f;
        for (int i = tid; i < nb; i += TPB) {
            s += partials[2*i];
            c += partials[2*i + 1];
        }
        #pragma unroll
        for (int d = 32; d >= 1; d >>= 1) {
            s += __shfl_xor(s, d, 64);
            c += __shfl_xor(c, d, 64);
        }
        if ((tid & 63) == 0) {
            rbuf[(tid >> 6)]     = s;
            rbuf[4 + (tid >> 6)] = c;
        }
        __syncthreads();
        if (tid == 0) {
            const float S = (rbuf[0] + rbuf[1]) + (rbuf[2] + rbuf[3]);
            const float C = (rbuf[4] + rbuf[5]) + (rbuf[6] + rbuf[7]);
            out[0] = S / fmaxf(C, 1.0f);
        }
    }
}

extern "C" void kernel_launch(void* const* d_in, const int* in_sizes, int n_in,
                              void* d_out, int out_size, void* d_ws, size_t ws_size,
                              hipStream_t stream)
{
    const float* scores = (const float*)d_in[0];
    const int*   ranks  = (const int*)d_in[1];
    const int*   mask   = (const int*)d_in[2];

    const int B  = in_sizes[0] / 32;
    const int nb = (B + TPB - 1) / TPB;

    unsigned* counter  = (unsigned*)d_ws;                     // 4 B
    float*    partials = (float*)((char*)d_ws + 16);          // nb*2 floats

    hipMemsetAsync(counter, 0, 4, stream);                    // graph-capturable
    pl_fused<<<nb, TPB, 0, stream>>>(scores, ranks, mask, partials, counter,
                                     (float*)d_out, B, nb);
}